// Round 1
// baseline (1416.344 us; speedup 1.0000x reference)
//
#include <hip/hip_runtime.h>
#include <hip/hip_bf16.h>

// EntityTable: B=16,T=2048,D=1024,N_E=8,D_E=64
// Phase A (parallel): hp = h@Wi^T + bi ; logits = h@ek^T/32 ; w = softmax(logits)
//                     P  = W_ih @ hp   (entity-independent input-gate projection)
// Phase B (sequential scan over T): per cell (b,n):
//   gx_k = w*P_k + b_ih_k ; gh_k = W_hh[k]·s + b_hh_k
//   r=sig(gx0+gh0) z=sig(gx1+gh1) n=tanh(gx2 + r*gh2) ; s' = (1-z)n + z s

constexpr int B_  = 16;
constexpr int T_  = 2048;
constexpr int D_  = 1024;
constexpr int NE  = 8;
constexpr int DE  = 64;
constexpr int G3  = 192;            // 3*DE
constexpr int ROWS = B_ * T_;       // 32768
constexpr int OUT1OFF = ROWS * NE * DE;  // 16777216

// ---------------- Kernel A: projection + routing + P ----------------
constexpr int RPB = 32;   // rows per block
constexpr int CH  = 128;  // K-chunk

__global__ __launch_bounds__(256) void proj_kernel(
    const float* __restrict__ h,   const float* __restrict__ ek,
    const float* __restrict__ Wi,  const float* __restrict__ bi,
    const float* __restrict__ Wih,
    float* __restrict__ Pout, float* __restrict__ wout)
{
    __shared__ float hch[RPB][CH];   // 16 KB
    __shared__ float hp[RPB][DE];    // 8 KB
    __shared__ float lg[RPB][NE];    // 1 KB

    const int tid = threadIdx.x;
    const int brow = blockIdx.x * RPB;
    const int w = tid >> 6;          // wave 0..3
    const int o = tid & 63;          // lane = output index for hp
    const int n  = o & 7;            // entity for logit partial
    const int sl = o >> 3;           // K-slice for logit partial

    float acc[8], accl[8];
#pragma unroll
    for (int r = 0; r < 8; ++r) { acc[r] = 0.f; accl[r] = 0.f; }

    for (int kc = 0; kc < D_; kc += CH) {
        __syncthreads();
        // cooperative load of h chunk: 32 rows x 128
#pragma unroll
        for (int i = 0; i < 4; ++i) {
            int idx = tid + i * 256;
            int lr = idx >> 5;
            int c4 = (idx & 31) * 4;
            *(float4*)&hch[lr][c4] =
                *(const float4*)&h[(size_t)(brow + lr) * D_ + kc + c4];
        }
        __syncthreads();

        // hp accumulation: lane o owns output o, 8 rows of its wave
        for (int d4 = 0; d4 < CH / 4; ++d4) {
            const float4 wi4 = *(const float4*)&Wi[o * D_ + kc + d4 * 4];
#pragma unroll
            for (int r = 0; r < 8; ++r) {
                const float4 h4 = *(const float4*)&hch[w * 8 + r][d4 * 4];
                acc[r] = fmaf(wi4.x, h4.x,
                         fmaf(wi4.y, h4.y,
                         fmaf(wi4.z, h4.z,
                         fmaf(wi4.w, h4.w, acc[r]))));
            }
        }
        // logits partial: lane handles entity n, K-slice sl (16 d's of this chunk)
#pragma unroll
        for (int i4 = 0; i4 < 4; ++i4) {
            const int dl = sl * 16 + i4 * 4;
            const float4 e4 = *(const float4*)&ek[n * D_ + kc + dl];
#pragma unroll
            for (int r = 0; r < 8; ++r) {
                const float4 h4 = *(const float4*)&hch[w * 8 + r][dl];
                accl[r] = fmaf(e4.x, h4.x,
                          fmaf(e4.y, h4.y,
                          fmaf(e4.z, h4.z,
                          fmaf(e4.w, h4.w, accl[r]))));
            }
        }
    }

    // finish hp -> LDS
    const float biv = bi[o];
#pragma unroll
    for (int r = 0; r < 8; ++r) hp[w * 8 + r][o] = acc[r] + biv;

    // reduce logit partials across the 8 K-slices (lanes with same o&7)
#pragma unroll
    for (int r = 0; r < 8; ++r) {
        accl[r] += __shfl_xor(accl[r], 8);
        accl[r] += __shfl_xor(accl[r], 16);
        accl[r] += __shfl_xor(accl[r], 32);
    }
    if (sl == 0) {
#pragma unroll
        for (int r = 0; r < 8; ++r) lg[w * 8 + r][n] = accl[r] * 0.03125f;
    }
    __syncthreads();

    // softmax over 8 entities (one thread per row)
    if (tid < RPB) {
        const int lr = tid;
        float v[NE];
        float m = -1e30f;
#pragma unroll
        for (int e = 0; e < NE; ++e) { v[e] = lg[lr][e]; m = fmaxf(m, v[e]); }
        float s = 0.f;
#pragma unroll
        for (int e = 0; e < NE; ++e) { v[e] = __expf(v[e] - m); s += v[e]; }
        const float inv = 1.f / s;
#pragma unroll
        for (int e = 0; e < NE; ++e)
            wout[(size_t)(brow + lr) * NE + e] = v[e] * inv;
    }

    // P = W_ih @ hp  (threads 0..191, k = thread)
    if (tid < G3) {
        const int k = tid;
        for (int lr0 = 0; lr0 < RPB; lr0 += 8) {
            float pacc[8];
#pragma unroll
            for (int r = 0; r < 8; ++r) pacc[r] = 0.f;
            for (int d4 = 0; d4 < DE / 4; ++d4) {
                const float4 wv = *(const float4*)&Wih[k * DE + d4 * 4];
#pragma unroll
                for (int r = 0; r < 8; ++r) {
                    const float4 h4 = *(const float4*)&hp[lr0 + r][d4 * 4];
                    pacc[r] = fmaf(wv.x, h4.x,
                              fmaf(wv.y, h4.y,
                              fmaf(wv.z, h4.z,
                              fmaf(wv.w, h4.w, pacc[r]))));
                }
            }
#pragma unroll
            for (int r = 0; r < 8; ++r)
                Pout[(size_t)(brow + lr0 + r) * G3 + k] = pacc[r];
        }
    }
}

// ---------------- Kernel B: sequential GRU scan ----------------
// 128 blocks (one per (b,n) cell), 384 threads: thread = (k, half)
__global__ __launch_bounds__(384) void scan_kernel(
    const float* __restrict__ P,   const float* __restrict__ route,
    const float* __restrict__ Whh, const float* __restrict__ bih,
    const float* __restrict__ bhh, const float* __restrict__ e0,
    float* __restrict__ out, int write1)
{
    __shared__ float s_lds[DE];
    __shared__ float a_lds[2 * DE];
    __shared__ float u_lds[DE];
    __shared__ float v_lds[DE];

    const int cell = blockIdx.x;
    const int b = cell >> 3;
    const int n = cell & 7;
    const int tid = threadIdx.x;
    const int k = tid >> 1;
    const int hh = tid & 1;

    // preload this thread's half-row of W_hh
    float wreg[32];
#pragma unroll
    for (int i4 = 0; i4 < 8; ++i4)
        *(float4*)&wreg[i4 * 4] = *(const float4*)&Whh[k * DE + hh * 32 + i4 * 4];
    const float bihk = bih[k];
    const float bhhk = bhh[k];

    const size_t row0 = (size_t)b * T_;

    float s_reg = 0.f;
    if (tid < DE) {
        s_reg = e0[n * DE + tid];
        s_lds[tid] = s_reg;
    }

    float wn = route[row0 * NE + n];
    float pn = P[row0 * G3 + k];
    __syncthreads();

    for (int t = 0; t < T_; ++t) {
        const float wcur = wn, pcur = pn;
        if (t + 1 < T_) {
            wn = route[(row0 + t + 1) * NE + n];
            pn = P[(row0 + t + 1) * G3 + k];
        }
        const float gx = fmaf(wcur, pcur, bihk);

        float a0 = 0.f, a1 = 0.f;
#pragma unroll
        for (int i4 = 0; i4 < 8; ++i4) {
            const float4 s4 = *(const float4*)&s_lds[hh * 32 + i4 * 4];
            a0 = fmaf(wreg[i4 * 4 + 0], s4.x, fmaf(wreg[i4 * 4 + 1], s4.y, a0));
            a1 = fmaf(wreg[i4 * 4 + 2], s4.z, fmaf(wreg[i4 * 4 + 3], s4.w, a1));
        }
        float g = a0 + a1;
        g += __shfl_xor(g, 1);
        g += bhhk;

        if (hh == 0) {
            if (k < 128) {
                a_lds[k] = gx + g;
            } else {
                u_lds[k - 128] = gx;
                v_lds[k - 128] = g;
            }
        }
        __syncthreads();

        if (tid < DE) {
            const int j = tid;
            const float rr = 1.f / (1.f + __expf(-a_lds[j]));
            const float zz = 1.f / (1.f + __expf(-a_lds[64 + j]));
            const float nn = tanhf(fmaf(rr, v_lds[j], u_lds[j]));
            const float snew = fmaf(zz, s_reg - nn, nn);  // (1-z)n + z s
            s_reg = snew;
            s_lds[j] = snew;
            const size_t o0 = (row0 + t) * (size_t)(NE * DE) + n * DE + j;
            out[o0] = snew;
            if (write1) out[OUT1OFF + o0] = snew;
        }
        __syncthreads();
    }
}

extern "C" void kernel_launch(void* const* d_in, const int* in_sizes, int n_in,
                              void* d_out, int out_size, void* d_ws, size_t ws_size,
                              hipStream_t stream) {
    const float* h_seq = (const float*)d_in[0];
    const float* ek    = (const float*)d_in[1];
    const float* Wi    = (const float*)d_in[2];
    const float* bi    = (const float*)d_in[3];
    const float* Wih   = (const float*)d_in[4];
    const float* Whh   = (const float*)d_in[5];
    const float* bih   = (const float*)d_in[6];
    const float* bhh   = (const float*)d_in[7];
    const float* e0    = (const float*)d_in[8];
    float* out = (float*)d_out;

    const size_t need = (size_t)ROWS * (G3 + NE) * sizeof(float);  // 26.2 MB
    float* wbuf;
    float* Pbuf;
    int write1;
    if (ws_size >= need) {
        wbuf = (float*)d_ws;
        Pbuf = wbuf + (size_t)ROWS * NE;
        write1 = 1;
    } else {
        // stash P/route in the out1 region; replicate out0->out1 at the end
        wbuf = out + OUT1OFF;
        Pbuf = wbuf + (size_t)ROWS * NE;
        write1 = 0;
    }

    proj_kernel<<<ROWS / RPB, 256, 0, stream>>>(h_seq, ek, Wi, bi, Wih, Pbuf, wbuf);
    scan_kernel<<<B_ * NE, 384, 0, stream>>>(Pbuf, wbuf, Whh, bih, bhh, e0, out, write1);

    if (!write1) {
        hipMemcpyAsync(out + OUT1OFF, out, (size_t)OUT1OFF * sizeof(float),
                       hipMemcpyDeviceToDevice, stream);
    }
}